// Round 21
// baseline (297.666 us; speedup 1.0000x reference)
//
#include <hip/hip_runtime.h>
#include <math.h>

// RiemannianBatchNorm, B=8192 SPD 64x64 fp32 — MFMA round 21.
// Base = round-20 (261.9us best, validated). ONE delta: REGISTER PREFETCH
// of the next matrix (async-stage split). Each iteration packs the
// pre-loaded registers into LDS, then immediately issues next matrix's
// global loads — HBM latency hides under the ~9-barrier poly pipeline.
// Applied to phaseC, phaseE1 (x) and phaseE2 (L; prefetched slot mloc-1
// < 2*mloc = below this iteration's out-write clobber region — safe).

#define NMAT 8192
#define NBLK 1024
#define MPB 8
#define PITCHF 68
#define FMSZ (64*PITCHF)
#define PITCHB 72
#define BMSZ (64*PITCHB)

typedef __attribute__((ext_vector_type(8))) short bf16x8;
typedef __attribute__((ext_vector_type(4))) float f32x4;

struct Poly16 { float m[16]; };

// ---------------- bf16 helpers (RNE, bit-identical to round 8) -------------
__device__ __forceinline__ unsigned rneu(float f) {
    union { float f; unsigned u; } v; v.f = f;
    return v.u + 0x7FFFu + ((v.u >> 16) & 1u);
}
__device__ __forceinline__ float bfu(unsigned h) {
    union { unsigned u; float f; } v; v.u = h << 16; return v.f;
}
__device__ __forceinline__ unsigned packpair(float a, float b) {
    unsigned r;
    asm("v_perm_b32 %0, %1, %2, %3"
        : "=v"(r) : "v"(rneu(b)), "v"(rneu(a)), "s"(0x07060302u));
    return r;
}
__device__ __forceinline__ uint2 pack4(float a, float b, float c, float d) {
    uint2 r; r.x = packpair(a, b); r.y = packpair(c, d); return r;
}

// ---------------- MFMA helpers (validated r10/r11/r14/r17) ----------------
__device__ __forceinline__ void mm_AB(const unsigned short* A, const bf16x8 bfr[8],
                                      f32x4 acc[4], int w, int lane) {
    const int lrow = lane & 15, lq = lane >> 4;
    const bf16x8 a0 = *(const bf16x8*)(A + (16*w + lrow)*PITCHB + 8*lq);
    const bf16x8 a1 = *(const bf16x8*)(A + (16*w + lrow)*PITCHB + 32 + 8*lq);
    #pragma unroll
    for (int n = 0; n < 4; ++n) {
        acc[n] = __builtin_amdgcn_mfma_f32_16x16x32_bf16(a0, bfr[2*n], acc[n], 0, 0, 0);
        acc[n] = __builtin_amdgcn_mfma_f32_16x16x32_bf16(a1, bfr[2*n+1], acc[n], 0, 0, 0);
    }
}
__device__ __forceinline__ void mm_LL(const unsigned short* A, const unsigned short* B,
                                      f32x4 acc[4], int w, int lane) {
    const int lrow = lane & 15, lq = lane >> 4;
    const bf16x8 a0 = *(const bf16x8*)(A + (16*w + lrow)*PITCHB + 8*lq);
    const bf16x8 a1 = *(const bf16x8*)(A + (16*w + lrow)*PITCHB + 32 + 8*lq);
    #pragma unroll
    for (int n = 0; n < 4; ++n) {
        const bf16x8 b0 = *(const bf16x8*)(B + (16*n + lrow)*PITCHB + 8*lq);
        const bf16x8 b1 = *(const bf16x8*)(B + (16*n + lrow)*PITCHB + 32 + 8*lq);
        acc[n] = __builtin_amdgcn_mfma_f32_16x16x32_bf16(a0, b0, acc[n], 0, 0, 0);
        acc[n] = __builtin_amdgcn_mfma_f32_16x16x32_bf16(a1, b1, acc[n], 0, 0, 0);
    }
}
__device__ __forceinline__ void load_frags(const unsigned short* B, bf16x8 bfr[8],
                                           int lane) {
    const int lrow = lane & 15, lq = lane >> 4;
    #pragma unroll
    for (int n = 0; n < 4; ++n) {
        bfr[2*n]   = *(const bf16x8*)(B + (16*n + lrow)*PITCHB + 8*lq);
        bfr[2*n+1] = *(const bf16x8*)(B + (16*n + lrow)*PITCHB + 32 + 8*lq);
    }
}
// store D transposed in true row-major (packed 8B writes)
__device__ __forceinline__ void store_sym(unsigned short* M, const f32x4 acc[4],
                                          int w, int lane) {
    const int lrow = lane & 15, lq = lane >> 4;
    #pragma unroll
    for (int n = 0; n < 4; ++n)
        *(uint2*)(M + (16*n + lrow)*PITCHB + 16*w + 4*lq) =
            pack4(acc[n][0], acc[n][1], acc[n][2], acc[n][3]);
}
// trace: ONE barrier (validated r20)
__device__ __forceinline__ float traceD(const f32x4 acc[4], float* red,
                                        int w, int lane) {
    const int lrow = lane & 15, lq = lane >> 4;
    float c = 0.f;
    #pragma unroll
    for (int n = 0; n < 4; ++n)
        #pragma unroll
        for (int r = 0; r < 4; ++r)
            if (n == w && lrow == 4*lq + r) c += acc[n][r];
    #pragma unroll
    for (int off = 32; off; off >>= 1) c += __shfl_xor(c, off);
    if (lane == 0) red[w] = c;
    __syncthreads();
    return red[0] + red[1] + red[2] + red[3];
}

// ---------------- log pipeline, x PRE-STAGED in W0 (barrier done) ----------
// W0: x -> u -> ping/pong;  W2: D1^T -> u^2 -> pong/ping.
template<int NCH>
__device__ __forceinline__ void log_core_staged(const bf16x8 sifr[8],
        unsigned short* W0, unsigned short* W2,
        float* red, const float* __restrict__ m, float invh, float cdh,
        f32x4 accL[4], int tid, int w, int lane)
{
    const int lrow = lane & 15, lq = lane >> 4;
    f32x4 acc[4];
    #pragma unroll
    for (int n = 0; n < 4; ++n) acc[n] = 0.f;
    mm_AB(W0, sifr, acc, w, lane);           // D1 = x * SI
    store_sym(W2, acc, w, lane);             // W2 <- D1^T = SI*x (true layout)
    __syncthreads();
    #pragma unroll
    for (int n = 0; n < 4; ++n) acc[n] = 0.f;
    mm_AB(W2, sifr, acc, w, lane);           // Y = (SI*x)*SI (symmetric)
    float tr = traceD(acc, red, w, lane);    // 1 barrier
    float s = 64.f / tr, ls = logf(s), sh = s * invh;
    f32x4 uD[4];
    #pragma unroll
    for (int n = 0; n < 4; ++n)
        #pragma unroll
        for (int r = 0; r < 4; ++r) {
            float v = sh * acc[n][r];
            if (n == w && lrow == 4*lq + r) v -= cdh;
            uD[n][r] = v;
        }
    store_sym(W0, uD, w, lane);              // W0 <- u (x dead)
    __syncthreads();
    #pragma unroll
    for (int n = 0; n < 4; ++n) acc[n] = 0.f;
    mm_LL(W0, W0, acc, w, lane);             // u^2
    store_sym(W2, acc, w, lane);             // W2 <- u^2 (D1^T dead)
    __syncthreads();
    bf16x8 ufr[8];
    load_frags(W2, ufr, lane);               // u^2 -> registers; W2 now free
    f32x4 cur[4];
    {
        float c1 = m[2*NCH-1], c0 = m[2*NCH-2];
        #pragma unroll
        for (int n = 0; n < 4; ++n)
            #pragma unroll
            for (int r = 0; r < 4; ++r) {
                float v = c1 * uD[n][r];
                if (n == w && lrow == 4*lq + r) v += c0;
                cur[n][r] = v;
            }
    }
    store_sym(W0, cur, w, lane);             // W0 <- C_{NCH-1}
    __syncthreads();
    unsigned short* ping = W0;
    unsigned short* pong = W2;               // u^2 buffer reused as pong
    #pragma unroll
    for (int i = NCH-2; i >= 0; --i) {
        f32x4 a2[4];
        #pragma unroll
        for (int n = 0; n < 4; ++n) a2[n] = 0.f;
        mm_AB(ping, ufr, a2, w, lane);       // cur * u^2
        float d1 = m[2*i+1];
        float d0 = m[2*i] + (i == 0 ? -ls : 0.f);
        #pragma unroll
        for (int n = 0; n < 4; ++n)
            #pragma unroll
            for (int r = 0; r < 4; ++r) {
                float v = a2[n][r] + d1 * uD[n][r];
                if (n == w && lrow == 4*lq + r) v += d0;
                a2[n][r] = v;
            }
        if (i > 0) {
            store_sym(pong, a2, w, lane);
            __syncthreads();
            unsigned short* t = ping; ping = pong; pong = t;
        } else {
            #pragma unroll
            for (int n = 0; n < 4; ++n) accL[n] = a2[n];
        }
    }
}

// ---------------- K: partial sums ----------------
__global__ __launch_bounds__(256) void k_psum(const float* __restrict__ src,
                                              float* __restrict__ Pbuf) {
    int g = blockIdx.x, tid = threadIdx.x;
    float4 acc[4];
    #pragma unroll
    for (int e = 0; e < 4; ++e) acc[e] = make_float4(0.f, 0.f, 0.f, 0.f);
    for (int b = 0; b < MPB; ++b) {
        const float4* sb = (const float4*)(src + ((size_t)g*MPB + b)*4096);
        #pragma unroll
        for (int e = 0; e < 4; ++e) {
            float4 v = sb[e*256 + tid];
            acc[e].x += v.x; acc[e].y += v.y; acc[e].z += v.z; acc[e].w += v.w;
        }
    }
    #pragma unroll
    for (int e = 0; e < 4; ++e)
        *(float4*)(Pbuf + (size_t)g*4096 + (size_t)(e*256 + tid)*4) = acc[e];
}

// ---------------- K: hierarchical reduce (compile-time trip counts) --------
__global__ __launch_bounds__(256) void k_red1(const float* __restrict__ Pbuf,
                                              float* __restrict__ Pbuf2) {
    int b = blockIdx.x;
    int gb = b >> 4, cb = b & 15;
    int idx = cb*256 + threadIdx.x;
    float s = 0.f;
    #pragma unroll 8
    for (int g = 0; g < 64; ++g)
        s += Pbuf[(size_t)(gb*64 + g)*4096 + idx];
    Pbuf2[(size_t)gb*4096 + idx] = s;
}
__global__ __launch_bounds__(256) void k_red2(const float* __restrict__ Pbuf2,
                                              float* __restrict__ out4096,
                                              float inv) {
    int idx = blockIdx.x*256 + threadIdx.x;
    float s = 0.f;
    #pragma unroll
    for (int gb = 0; gb < 16; ++gb) s += Pbuf2[(size_t)gb*4096 + idx];
    out4096[idx] = s * inv;
}

// ---------------- fp32 helpers for prep kernels ----------------
__device__ __forceinline__ void mm_tile(const float* __restrict__ A,
                                        const float* __restrict__ B,
                                        float acc[16], int ti, int tj) {
    #pragma unroll
    for (int e = 0; e < 16; ++e) acc[e] = 0.f;
    const float* Ab = A + (4*ti)*PITCHF;
    const float* Bb = B + 4*tj;
    #pragma unroll 4
    for (int k0 = 0; k0 < 64; k0 += 4) {
        float4 a0 = *(const float4*)(Ab + 0*PITCHF + k0);
        float4 a1 = *(const float4*)(Ab + 1*PITCHF + k0);
        float4 a2 = *(const float4*)(Ab + 2*PITCHF + k0);
        float4 a3 = *(const float4*)(Ab + 3*PITCHF + k0);
        float4 b0 = *(const float4*)(Bb + (k0+0)*PITCHF);
        float4 b1 = *(const float4*)(Bb + (k0+1)*PITCHF);
        float4 b2 = *(const float4*)(Bb + (k0+2)*PITCHF);
        float4 b3 = *(const float4*)(Bb + (k0+3)*PITCHF);
#define MMROW(RO, AV) \
        acc[RO+0] += AV.x*b0.x + AV.y*b1.x + AV.z*b2.x + AV.w*b3.x; \
        acc[RO+1] += AV.x*b0.y + AV.y*b1.y + AV.z*b2.y + AV.w*b3.y; \
        acc[RO+2] += AV.x*b0.z + AV.y*b1.z + AV.z*b2.z + AV.w*b3.z; \
        acc[RO+3] += AV.x*b0.w + AV.y*b1.w + AV.z*b2.w + AV.w*b3.w;
        MMROW(0, a0) MMROW(4, a1) MMROW(8, a2) MMROW(12, a3)
#undef MMROW
    }
}
__device__ __forceinline__ void store_tile(float* __restrict__ D,
                                           const float acc[16], int ti, int tj) {
    #pragma unroll
    for (int r = 0; r < 4; ++r) {
        float4 v = make_float4(acc[r*4+0], acc[r*4+1], acc[r*4+2], acc[r*4+3]);
        *(float4*)(D + (4*ti+r)*PITCHF + 4*tj) = v;
    }
}
__device__ __forceinline__ float block_trace64(const float* __restrict__ W,
                                               float* red, int tid) {
    if (tid < 64) {
        float v = W[tid*PITCHF + tid];
        #pragma unroll
        for (int off = 32; off; off >>= 1) v += __shfl_xor(v, off);
        if (tid == 0) red[0] = v;
    }
    __syncthreads();
    float t = red[0];
    __syncthreads();
    return t;
}

// ---------------- K: S = M0^{1/2}, SI = M0^{-1/2} ----------------
__global__ __launch_bounds__(256) void k_prep1(const float* __restrict__ M0,
                                               float* __restrict__ S,
                                               float* __restrict__ SI) {
    __shared__ __align__(16) float WS[4*FMSZ];
    __shared__ float red[256];
    float* W0 = WS; float* W1 = WS + FMSZ; float* W2 = WS + 2*FMSZ; float* W3 = WS + 3*FMSZ;
    int tid = threadIdx.x;
    int ti = tid >> 4, tj = tid & 15;
    const float4* s4 = (const float4*)M0;
    #pragma unroll
    for (int e = 0; e < 4; ++e) {
        int idx = e*256 + tid;
        *(float4*)(W0 + (idx>>4)*PITCHF + (idx&15)*4) = s4[idx];
    }
    __syncthreads();
    float m = block_trace64(W0, red, tid) * (1.f/64.f);
    float im = 1.f/m;
    #pragma unroll
    for (int r = 0; r < 4; ++r) {
        float4 v = *(const float4*)(W0 + (4*ti+r)*PITCHF + 4*tj);
        v.x *= im; v.y *= im; v.z *= im; v.w *= im;
        if (ti == tj) ((float*)&v)[r] -= 1.f;
        *(float4*)(W0 + (4*ti+r)*PITCHF + 4*tj) = v;
    }
    __syncthreads();
    float acc[16];
    mm_tile(W0, W0, acc, ti, tj); store_tile(W1, acc, ti, tj); __syncthreads();
    mm_tile(W0, W1, acc, ti, tj); store_tile(W2, acc, ti, tj); __syncthreads();
    mm_tile(W1, W1, acc, ti, tj); store_tile(W3, acc, ti, tj); __syncthreads();
    float sm = sqrtf(m), rm = rsqrtf(m);
    #pragma unroll
    for (int r = 0; r < 4; ++r) {
        float4 e1 = *(const float4*)(W0 + (4*ti+r)*PITCHF + 4*tj);
        float4 e2 = *(const float4*)(W1 + (4*ti+r)*PITCHF + 4*tj);
        float4 e3 = *(const float4*)(W2 + (4*ti+r)*PITCHF + 4*tj);
        float4 e4 = *(const float4*)(W3 + (4*ti+r)*PITCHF + 4*tj);
        float4 sv, iv;
        #pragma unroll
        for (int c = 0; c < 4; ++c) {
            float E1 = ((float*)&e1)[c], E2 = ((float*)&e2)[c];
            float E3 = ((float*)&e3)[c], E4 = ((float*)&e4)[c];
            float d = (ti == tj && c == r) ? 1.f : 0.f;
            ((float*)&sv)[c] = sm*(d + 0.5f*E1 - 0.125f*E2 + 0.0625f*E3 - 0.0390625f*E4);
            ((float*)&iv)[c] = rm*(d - 0.5f*E1 + 0.375f*E2 - 0.3125f*E3 + 0.2734375f*E4);
        }
        *(float4*)(S  + (4*ti+r)*64 + 4*tj) = sv;
        *(float4*)(SI + (4*ti+r)*64 + 4*tj) = iv;
    }
}

// ---------------- K: expT, mean = S expT S, MI = mean^{-1/2} ----------------
__global__ __launch_bounds__(256) void k_prep2(const float* __restrict__ T,
                                               const float* __restrict__ S,
                                               float* __restrict__ MI) {
    __shared__ __align__(16) float WS[4*FMSZ];
    __shared__ float red[256];
    float* W0 = WS; float* W1 = WS + FMSZ; float* W2 = WS + 2*FMSZ; float* W3 = WS + 3*FMSZ;
    int tid = threadIdx.x;
    int ti = tid >> 4, tj = tid & 15;
    const float4* t4 = (const float4*)T;
    #pragma unroll
    for (int e = 0; e < 4; ++e) {
        int idx = e*256 + tid;
        *(float4*)(W0 + (idx>>4)*PITCHF + (idx&15)*4) = t4[idx];
    }
    __syncthreads();
    float g = block_trace64(W0, red, tid) * (1.f/64.f);
    if (ti == tj) {
        #pragma unroll
        for (int r = 0; r < 4; ++r) W0[(4*ti+r)*PITCHF + 4*tj + r] -= g;
    }
    __syncthreads();
    float acc[16];
    mm_tile(W0, W0, acc, ti, tj); store_tile(W1, acc, ti, tj); __syncthreads();
    mm_tile(W0, W1, acc, ti, tj); store_tile(W2, acc, ti, tj); __syncthreads();
    mm_tile(W1, W1, acc, ti, tj); store_tile(W3, acc, ti, tj); __syncthreads();
    float eg = expf(g);
    #pragma unroll
    for (int r = 0; r < 4; ++r) {
        float4 f1 = *(const float4*)(W0 + (4*ti+r)*PITCHF + 4*tj);
        float4 f2 = *(const float4*)(W1 + (4*ti+r)*PITCHF + 4*tj);
        float4 f3 = *(const float4*)(W2 + (4*ti+r)*PITCHF + 4*tj);
        float4 f4 = *(const float4*)(W3 + (4*ti+r)*PITCHF + 4*tj);
        float4 v;
        #pragma unroll
        for (int c = 0; c < 4; ++c) {
            float d = (ti == tj && c == r) ? 1.f : 0.f;
            ((float*)&v)[c] = eg*(d + ((float*)&f1)[c] + 0.5f*((float*)&f2)[c]
                                  + (1.f/6.f)*((float*)&f3)[c] + (1.f/24.f)*((float*)&f4)[c]);
        }
        *(float4*)(W1 + (4*ti+r)*PITCHF + 4*tj) = v;
    }
    __syncthreads();
    const float4* s4 = (const float4*)S;
    #pragma unroll
    for (int e = 0; e < 4; ++e) {
        int idx = e*256 + tid;
        *(float4*)(W2 + (idx>>4)*PITCHF + (idx&15)*4) = s4[idx];
    }
    __syncthreads();
    mm_tile(W2, W1, acc, ti, tj); store_tile(W3, acc, ti, tj); __syncthreads();
    mm_tile(W3, W2, acc, ti, tj); store_tile(W0, acc, ti, tj); __syncthreads();
    float m2 = block_trace64(W0, red, tid) * (1.f/64.f);
    float im2 = 1.f/m2;
    #pragma unroll
    for (int r = 0; r < 4; ++r) {
        float4 v = *(const float4*)(W0 + (4*ti+r)*PITCHF + 4*tj);
        v.x *= im2; v.y *= im2; v.z *= im2; v.w *= im2;
        if (ti == tj) ((float*)&v)[r] -= 1.f;
        *(float4*)(W0 + (4*ti+r)*PITCHF + 4*tj) = v;
    }
    __syncthreads();
    mm_tile(W0, W0, acc, ti, tj); store_tile(W1, acc, ti, tj); __syncthreads();
    mm_tile(W0, W1, acc, ti, tj); store_tile(W2, acc, ti, tj); __syncthreads();
    mm_tile(W1, W1, acc, ti, tj); store_tile(W3, acc, ti, tj); __syncthreads();
    float rm = rsqrtf(m2);
    #pragma unroll
    for (int r = 0; r < 4; ++r) {
        float4 g1 = *(const float4*)(W0 + (4*ti+r)*PITCHF + 4*tj);
        float4 g2 = *(const float4*)(W1 + (4*ti+r)*PITCHF + 4*tj);
        float4 g3 = *(const float4*)(W2 + (4*ti+r)*PITCHF + 4*tj);
        float4 g4 = *(const float4*)(W3 + (4*ti+r)*PITCHF + 4*tj);
        float4 v;
        #pragma unroll
        for (int c = 0; c < 4; ++c) {
            float d = (ti == tj && c == r) ? 1.f : 0.f;
            ((float*)&v)[c] = rm*(d - 0.5f*((float*)&g1)[c] + 0.375f*((float*)&g2)[c]
                                  - 0.3125f*((float*)&g3)[c] + 0.2734375f*((float*)&g4)[c]);
        }
        *(float4*)(MI + (4*ti+r)*64 + 4*tj) = v;
    }
}

// ---------------- K: phase C — deg-9, x register-prefetch ------------------
__global__ __launch_bounds__(256, 4) void k_phaseC(const float* __restrict__ x,
        const float* __restrict__ SI, float* __restrict__ Pbuf,
        const Poly16 PL, float invh, float cdh) {
    __shared__ __align__(16) unsigned short W0[BMSZ], W2[BMSZ];
    __shared__ float red[4];
    const int tid = threadIdx.x, w = tid >> 6, lane = tid & 63;
    const int lrow = lane & 15, lq = lane >> 4;
    const float4* si4 = (const float4*)SI;
    #pragma unroll
    for (int e = 0; e < 4; ++e) {
        int idx = e*256 + tid;
        float4 sv = si4[idx];
        *(uint2*)(W0 + (idx>>4)*PITCHB + (idx&15)*4) = pack4(sv.x, sv.y, sv.z, sv.w);
    }
    __syncthreads();
    bf16x8 sifr[8];
    load_frags(W0, sifr, lane);
    // preload matrix 0 into registers
    float4 xr[4];
    {
        const float4* xb = (const float4*)(x + (size_t)blockIdx.x*MPB*4096);
        #pragma unroll
        for (int e = 0; e < 4; ++e) xr[e] = xb[e*256 + tid];
    }
    f32x4 lacc[4];
    #pragma unroll
    for (int n = 0; n < 4; ++n) lacc[n] = 0.f;
    for (int mloc = 0; mloc < MPB; ++mloc) {
        __syncthreads();   // frag reads / previous-iter readers done
        // pack prefetched x -> W0
        #pragma unroll
        for (int e = 0; e < 4; ++e) {
            int idx = e*256 + tid;
            *(uint2*)(W0 + (idx>>4)*PITCHB + (idx&15)*4) =
                pack4(xr[e].x, xr[e].y, xr[e].z, xr[e].w);
        }
        // issue next matrix's loads (latency hides under the poly pipeline)
        if (mloc + 1 < MPB) {
            const float4* xbn = (const float4*)(x + ((size_t)blockIdx.x*MPB + mloc + 1)*4096);
            #pragma unroll
            for (int e = 0; e < 4; ++e) xr[e] = xbn[e*256 + tid];
        }
        __syncthreads();
        f32x4 accL[4];
        log_core_staged<5>(sifr, W0, W2, red, PL.m, invh, cdh, accL, tid, w, lane);
        #pragma unroll
        for (int n = 0; n < 4; ++n) lacc[n] += accL[n];
    }
    float* pb = Pbuf + (size_t)blockIdx.x*4096;
    #pragma unroll
    for (int n = 0; n < 4; ++n)
        *(float4*)(pb + (16*n + lrow)*64 + 16*w + 4*lq) =
            make_float4(lacc[n][0], lacc[n][1], lacc[n][2], lacc[n][3]);
}

// ---------------- K: phase E1 — deg-9, x register-prefetch -----------------
__global__ __launch_bounds__(256, 4) void k_phaseE1(const float* __restrict__ x,
        const float* __restrict__ MIm, float* __restrict__ Dist,
        unsigned short* Lbf, const Poly16 PL, float invh, float cdh) {
    __shared__ __align__(16) unsigned short W0[BMSZ], W2[BMSZ];
    __shared__ float red[4];
    const int tid = threadIdx.x, w = tid >> 6, lane = tid & 63;
    const int lrow = lane & 15, lq = lane >> 4;
    const float4* mi4 = (const float4*)MIm;
    #pragma unroll
    for (int e = 0; e < 4; ++e) {
        int idx = e*256 + tid;
        float4 sv = mi4[idx];
        *(uint2*)(W0 + (idx>>4)*PITCHB + (idx&15)*4) = pack4(sv.x, sv.y, sv.z, sv.w);
    }
    __syncthreads();
    bf16x8 sifr[8];
    load_frags(W0, sifr, lane);
    float4 xr[4];
    {
        const float4* xb = (const float4*)(x + (size_t)blockIdx.x*MPB*4096);
        #pragma unroll
        for (int e = 0; e < 4; ++e) xr[e] = xb[e*256 + tid];
    }
    for (int mloc = 0; mloc < MPB; ++mloc) {
        size_t b = (size_t)blockIdx.x*MPB + mloc;
        __syncthreads();
        #pragma unroll
        for (int e = 0; e < 4; ++e) {
            int idx = e*256 + tid;
            *(uint2*)(W0 + (idx>>4)*PITCHB + (idx&15)*4) =
                pack4(xr[e].x, xr[e].y, xr[e].z, xr[e].w);
        }
        if (mloc + 1 < MPB) {
            const float4* xbn = (const float4*)(x + (b + 1)*4096);
            #pragma unroll
            for (int e = 0; e < 4; ++e) xr[e] = xbn[e*256 + tid];
        }
        __syncthreads();
        f32x4 accL[4];
        log_core_staged<5>(sifr, W0, W2, red, PL.m, invh, cdh, accL, tid, w, lane);
        float sq = 0.f;
        #pragma unroll
        for (int n = 0; n < 4; ++n)
            #pragma unroll
            for (int r = 0; r < 4; ++r) sq += accL[n][r]*accL[n][r];
        #pragma unroll
        for (int off = 32; off; off >>= 1) sq += __shfl_xor(sq, off);
        if (lane == 0) red[w] = sq;
        __syncthreads();
        if (tid == 0) Dist[b] = red[0] + red[1] + red[2] + red[3];
        unsigned short* Lb = Lbf + (size_t)blockIdx.x*65536 + (size_t)mloc*4096;
        #pragma unroll
        for (int n = 0; n < 4; ++n)
            *(uint2*)(Lb + (16*n + lrow)*64 + 16*w + 4*lq) =
                pack4(accL[n][0], accL[n][1], accL[n][2], accL[n][3]);
    }
}

// ---------------- K: var/std/p ----------------
__global__ __launch_bounds__(256) void k_var(const float* __restrict__ Dist,
                                             const float* __restrict__ scale,
                                             float* __restrict__ PV) {
    __shared__ float red[256];
    int tid = threadIdx.x;
    float s = 0.f;
    for (int k = tid; k < NMAT; k += 256) s += Dist[k];
    red[tid] = s;
    __syncthreads();
    for (int off = 128; off > 0; off >>= 1) {
        if (tid < off) red[tid] += red[tid + off];
        __syncthreads();
    }
    if (tid == 0) {
        float var = red[0] / (float)NMAT;
        PV[0] = scale[0] / (sqrtf(var) + 1e-5f);
    }
}

// ---------------- K: phase E2 — deg-5, L register-prefetch -----------------
// Descending mloc; prefetched L slot (mloc-1) < 2*mloc = below this
// iteration's out-write clobber region {2mloc, 2mloc+1} -> safe.
__global__ __launch_bounds__(256, 4) void k_phaseE2(const unsigned short* __restrict__ Lbf,
        const float* __restrict__ PV, float* __restrict__ out, const Poly16 PE) {
    __shared__ __align__(16) unsigned short W0[BMSZ], W1[BMSZ];
    const int tid = threadIdx.x, w = tid >> 6, lane = tid & 63;
    const int lrow = lane & 15, lq = lane >> 4;
    const float p = PV[0];
    uint2 qr[4];
    {
        const uint2* Lp = (const uint2*)(Lbf + (size_t)blockIdx.x*65536 + (size_t)(MPB-1)*4096);
        #pragma unroll
        for (int e = 0; e < 4; ++e) qr[e] = Lp[e*256 + tid];
    }
    for (int mloc = MPB-1; mloc >= 0; --mloc) {
        size_t b = (size_t)blockIdx.x*MPB + mloc;
        __syncthreads();
        #pragma unroll
        for (int e = 0; e < 4; ++e) {
            int idx = e*256 + tid;
            uint2 q = qr[e];
            *(uint2*)(W0 + (idx>>4)*PITCHB + (idx&15)*4) =
                pack4(p*bfu(q.x & 0xffffu), p*bfu(q.x >> 16),
                      p*bfu(q.y & 0xffffu), p*bfu(q.y >> 16));
        }
        if (mloc > 0) {
            const uint2* Lpn = (const uint2*)(Lbf + (size_t)blockIdx.x*65536 + (size_t)(mloc-1)*4096);
            #pragma unroll
            for (int e = 0; e < 4; ++e) qr[e] = Lpn[e*256 + tid];
        }
        __syncthreads();
        f32x4 MD[4];
        #pragma unroll
        for (int n = 0; n < 4; ++n) {
            uint2 q = *(const uint2*)(W0 + (16*n + lrow)*PITCHB + 16*w + 4*lq);
            MD[n][0] = bfu(q.x & 0xffffu);
            MD[n][1] = bfu(q.x >> 16);
            MD[n][2] = bfu(q.y & 0xffffu);
            MD[n][3] = bfu(q.y >> 16);
        }
        f32x4 acc[4];
        #pragma unroll
        for (int n = 0; n < 4; ++n) acc[n] = 0.f;
        mm_LL(W0, W0, acc, w, lane);               // M^2
        store_sym(W1, acc, w, lane);
        __syncthreads();
        bf16x8 mfr[8];
        load_frags(W1, mfr, lane);                 // M^2 -> regs; W1 free
        f32x4 cur[4];
        {
            float c1 = PE.m[5], c0 = PE.m[4];
            #pragma unroll
            for (int n = 0; n < 4; ++n)
                #pragma unroll
                for (int r = 0; r < 4; ++r) {
                    float v = c1 * MD[n][r];
                    if (n == w && lrow == 4*lq + r) v += c0;
                    cur[n][r] = v;
                }
        }
        store_sym(W0, cur, w, lane);               // M reads done pre-barrier
        __syncthreads();
        unsigned short* ping = W0;
        unsigned short* pong = W1;
        f32x4 accO[4];
        #pragma unroll
        for (int i = 1; i >= 0; --i) {
            f32x4 a2[4];
            #pragma unroll
            for (int n = 0; n < 4; ++n) a2[n] = 0.f;
            mm_AB(ping, mfr, a2, w, lane);
            float d1 = PE.m[2*i+1], d0 = PE.m[2*i];
            #pragma unroll
            for (int n = 0; n < 4; ++n)
                #pragma unroll
                for (int r = 0; r < 4; ++r) {
                    float v = a2[n][r] + d1 * MD[n][r];
                    if (n == w && lrow == 4*lq + r) v += d0;
                    a2[n][r] = v;
                }
            if (i > 0) {
                store_sym(pong, a2, w, lane);
                __syncthreads();
                unsigned short* t = ping; ping = pong; pong = t;
            } else {
                #pragma unroll
                for (int n = 0; n < 4; ++n) accO[n] = a2[n];
            }
        }
        float* ob = out + b*4096;
        #pragma unroll
        for (int n = 0; n < 4; ++n)
            *(float4*)(ob + (16*n + lrow)*64 + 16*w + 4*lq) =
                make_float4(accO[n][0], accO[n][1], accO[n][2], accO[n][3]);
    }
}

// ---------------- host launch ----------------
extern "C" void kernel_launch(void* const* d_in, const int* in_sizes, int n_in,
                              void* d_out, int out_size, void* d_ws, size_t ws_size,
                              hipStream_t stream) {
    const float* x = (const float*)d_in[0];
    const float* scale = (const float*)d_in[1];
    float* out = (float*)d_out;
    float* ws = (float*)d_ws;

    float* M0  = ws;            // 4096
    float* S   = M0 + 4096;     // 4096
    float* SI  = S + 4096;      // 4096
    float* T   = SI + 4096;     // 4096
    float* MIm = T + 4096;      // 4096
    float* DIST = MIm + 4096;   // 8192
    float* PV  = DIST + NMAT;   // 1
    float* Pbuf  = out;                            // 1024 partials
    float* Pbuf2 = out + (size_t)1024*4096;        // 16 stage-1 partials
    unsigned short* Lbf = (unsigned short*)d_out;  // region-interleaved L

    // exact Chebyshev-of-log on [0.25, 3.8] -> monomial coeffs (host, double)
    const double A = 0.25, B = 3.8;
    const double ccd = 0.5*(A+B), hhd = 0.5*(B-A);
    const double Md = ccd/hhd;
    const double tau = Md - sqrt(Md*Md - 1.0);
    double ac[16];
    ac[0] = log(hhd/(2.0*tau));
    {
        double tp = 1.0;
        for (int n = 1; n < 16; ++n) { tp *= -tau; ac[n] = -2.0*tp/(double)n; }
    }
    double Tm[16][16];
    for (int i = 0; i < 16; ++i) for (int k = 0; k < 16; ++k) Tm[i][k] = 0.0;
    Tm[0][0] = 1.0; Tm[1][1] = 1.0;
    for (int n = 2; n < 16; ++n)
        for (int k = 0; k <= n; ++k)
            Tm[n][k] = 2.0*(k > 0 ? Tm[n-1][k-1] : 0.0) - Tm[n-2][k];
    double m9[16];
    for (int k = 0; k < 16; ++k) m9[k] = 0.0;
    for (int n = 0; n < 10; ++n)
        for (int k = 0; k <= n; ++k) m9[k] += ac[n]*Tm[n][k];
    Poly16 PL9, PEXP;
    for (int k = 0; k < 16; ++k) { PL9.m[k] = (float)m9[k]; PEXP.m[k] = 0.f; }
    double fact = 1.0;
    for (int k = 0; k < 6; ++k) {            // deg-5 Taylor
        if (k > 0) fact *= (double)k;
        PEXP.m[k] = (float)(1.0/fact);
    }
    const float invh = (float)(1.0/hhd);
    const float cdh  = (float)(ccd/hhd);

    k_psum<<<NBLK, 256, 0, stream>>>(x, Pbuf);
    k_red1<<<256, 256, 0, stream>>>(Pbuf, Pbuf2);
    k_red2<<<16, 256, 0, stream>>>(Pbuf2, M0, 1.f/(float)NMAT);
    k_prep1<<<1, 256, 0, stream>>>(M0, S, SI);
    k_phaseC<<<NBLK, 256, 0, stream>>>(x, SI, Pbuf, PL9, invh, cdh);
    k_red1<<<256, 256, 0, stream>>>(Pbuf, Pbuf2);
    k_red2<<<16, 256, 0, stream>>>(Pbuf2, T, 1.f/(float)NMAT);
    k_prep2<<<1, 256, 0, stream>>>(T, S, MIm);
    k_phaseE1<<<NBLK, 256, 0, stream>>>(x, MIm, DIST, Lbf, PL9, invh, cdh);
    k_var<<<1, 256, 0, stream>>>(DIST, scale, PV);
    k_phaseE2<<<NBLK, 256, 0, stream>>>(Lbf, PV, out, PEXP);
}

// Round 22
// 261.523 us; speedup vs baseline: 1.1382x; 1.1382x over previous
//
#include <hip/hip_runtime.h>
#include <math.h>

// RiemannianBatchNorm, B=8192 SPD 64x64 fp32 — round 22 = round-20 verbatim
// (best validated: 261.9us, absmax 0.0078125). Round-21's register prefetch
// REGRESSED (compiler rematerialized the prefetch loads after the barrier:
// FETCH_SIZE doubled 89->193MB, phaseC 82->101us) and is reverted.
// Final structure: eigh-free matmul-polynomial pipeline, bf16 MFMA
// (16x16x32), D1-transpose trick, 2 LDS buffers/block, deg-9 Chebyshev log,
// deg-5 Taylor exp, hierarchical reduces, single-barrier trace.

#define NMAT 8192
#define NBLK 1024
#define MPB 8
#define PITCHF 68
#define FMSZ (64*PITCHF)
#define PITCHB 72
#define BMSZ (64*PITCHB)

typedef __attribute__((ext_vector_type(8))) short bf16x8;
typedef __attribute__((ext_vector_type(4))) float f32x4;

struct Poly16 { float m[16]; };

// ---------------- bf16 helpers (RNE) ----------------
__device__ __forceinline__ unsigned rneu(float f) {
    union { float f; unsigned u; } v; v.f = f;
    return v.u + 0x7FFFu + ((v.u >> 16) & 1u);
}
__device__ __forceinline__ float bfu(unsigned h) {
    union { unsigned u; float f; } v; v.u = h << 16; return v.f;
}
__device__ __forceinline__ unsigned packpair(float a, float b) {
    unsigned r;
    asm("v_perm_b32 %0, %1, %2, %3"
        : "=v"(r) : "v"(rneu(b)), "v"(rneu(a)), "s"(0x07060302u));
    return r;
}
__device__ __forceinline__ uint2 pack4(float a, float b, float c, float d) {
    uint2 r; r.x = packpair(a, b); r.y = packpair(c, d); return r;
}

// ---------------- MFMA helpers ----------------
__device__ __forceinline__ void mm_AB(const unsigned short* A, const bf16x8 bfr[8],
                                      f32x4 acc[4], int w, int lane) {
    const int lrow = lane & 15, lq = lane >> 4;
    const bf16x8 a0 = *(const bf16x8*)(A + (16*w + lrow)*PITCHB + 8*lq);
    const bf16x8 a1 = *(const bf16x8*)(A + (16*w + lrow)*PITCHB + 32 + 8*lq);
    #pragma unroll
    for (int n = 0; n < 4; ++n) {
        acc[n] = __builtin_amdgcn_mfma_f32_16x16x32_bf16(a0, bfr[2*n], acc[n], 0, 0, 0);
        acc[n] = __builtin_amdgcn_mfma_f32_16x16x32_bf16(a1, bfr[2*n+1], acc[n], 0, 0, 0);
    }
}
__device__ __forceinline__ void mm_LL(const unsigned short* A, const unsigned short* B,
                                      f32x4 acc[4], int w, int lane) {
    const int lrow = lane & 15, lq = lane >> 4;
    const bf16x8 a0 = *(const bf16x8*)(A + (16*w + lrow)*PITCHB + 8*lq);
    const bf16x8 a1 = *(const bf16x8*)(A + (16*w + lrow)*PITCHB + 32 + 8*lq);
    #pragma unroll
    for (int n = 0; n < 4; ++n) {
        const bf16x8 b0 = *(const bf16x8*)(B + (16*n + lrow)*PITCHB + 8*lq);
        const bf16x8 b1 = *(const bf16x8*)(B + (16*n + lrow)*PITCHB + 32 + 8*lq);
        acc[n] = __builtin_amdgcn_mfma_f32_16x16x32_bf16(a0, b0, acc[n], 0, 0, 0);
        acc[n] = __builtin_amdgcn_mfma_f32_16x16x32_bf16(a1, b1, acc[n], 0, 0, 0);
    }
}
__device__ __forceinline__ void load_frags(const unsigned short* B, bf16x8 bfr[8],
                                           int lane) {
    const int lrow = lane & 15, lq = lane >> 4;
    #pragma unroll
    for (int n = 0; n < 4; ++n) {
        bfr[2*n]   = *(const bf16x8*)(B + (16*n + lrow)*PITCHB + 8*lq);
        bfr[2*n+1] = *(const bf16x8*)(B + (16*n + lrow)*PITCHB + 32 + 8*lq);
    }
}
// store D transposed in true row-major (packed 8B writes)
__device__ __forceinline__ void store_sym(unsigned short* M, const f32x4 acc[4],
                                          int w, int lane) {
    const int lrow = lane & 15, lq = lane >> 4;
    #pragma unroll
    for (int n = 0; n < 4; ++n)
        *(uint2*)(M + (16*n + lrow)*PITCHB + 16*w + 4*lq) =
            pack4(acc[n][0], acc[n][1], acc[n][2], acc[n][3]);
}
// trace: ONE barrier (validated r20)
__device__ __forceinline__ float traceD(const f32x4 acc[4], float* red,
                                        int w, int lane) {
    const int lrow = lane & 15, lq = lane >> 4;
    float c = 0.f;
    #pragma unroll
    for (int n = 0; n < 4; ++n)
        #pragma unroll
        for (int r = 0; r < 4; ++r)
            if (n == w && lrow == 4*lq + r) c += acc[n][r];
    #pragma unroll
    for (int off = 32; off; off >>= 1) c += __shfl_xor(c, off);
    if (lane == 0) red[w] = c;
    __syncthreads();
    return red[0] + red[1] + red[2] + red[3];
}

// ---------------- log pipeline, 2 LDS buffers: W0 and W2 --------------------
template<int NCH>
__device__ __forceinline__ void log_core(const float4* __restrict__ xb,
        const bf16x8 sifr[8],
        unsigned short* W0, unsigned short* W2,
        float* red, const float* __restrict__ m, float invh, float cdh,
        f32x4 accL[4], int tid, int w, int lane)
{
    const int lrow = lane & 15, lq = lane >> 4;
    // stage x -> W0
    #pragma unroll
    for (int e = 0; e < 4; ++e) {
        int idx = e*256 + tid;
        float4 xv = xb[idx];
        *(uint2*)(W0 + (idx>>4)*PITCHB + (idx&15)*4) = pack4(xv.x, xv.y, xv.z, xv.w);
    }
    __syncthreads();
    f32x4 acc[4];
    #pragma unroll
    for (int n = 0; n < 4; ++n) acc[n] = 0.f;
    mm_AB(W0, sifr, acc, w, lane);           // D1 = x * SI
    store_sym(W2, acc, w, lane);             // W2 <- D1^T = SI*x (true layout)
    __syncthreads();
    #pragma unroll
    for (int n = 0; n < 4; ++n) acc[n] = 0.f;
    mm_AB(W2, sifr, acc, w, lane);           // Y = (SI*x)*SI (symmetric)
    float tr = traceD(acc, red, w, lane);    // 1 barrier
    float s = 64.f / tr, ls = logf(s), sh = s * invh;
    f32x4 uD[4];
    #pragma unroll
    for (int n = 0; n < 4; ++n)
        #pragma unroll
        for (int r = 0; r < 4; ++r) {
            float v = sh * acc[n][r];
            if (n == w && lrow == 4*lq + r) v -= cdh;
            uD[n][r] = v;
        }
    store_sym(W0, uD, w, lane);              // W0 <- u (x dead)
    __syncthreads();
    #pragma unroll
    for (int n = 0; n < 4; ++n) acc[n] = 0.f;
    mm_LL(W0, W0, acc, w, lane);             // u^2
    store_sym(W2, acc, w, lane);             // W2 <- u^2 (D1^T dead)
    __syncthreads();
    bf16x8 ufr[8];
    load_frags(W2, ufr, lane);               // u^2 -> registers; W2 now free
    f32x4 cur[4];
    {
        float c1 = m[2*NCH-1], c0 = m[2*NCH-2];
        #pragma unroll
        for (int n = 0; n < 4; ++n)
            #pragma unroll
            for (int r = 0; r < 4; ++r) {
                float v = c1 * uD[n][r];
                if (n == w && lrow == 4*lq + r) v += c0;
                cur[n][r] = v;
            }
    }
    store_sym(W0, cur, w, lane);             // W0 <- C_{NCH-1}
    __syncthreads();
    unsigned short* ping = W0;
    unsigned short* pong = W2;               // u^2 buffer reused as pong
    #pragma unroll
    for (int i = NCH-2; i >= 0; --i) {
        f32x4 a2[4];
        #pragma unroll
        for (int n = 0; n < 4; ++n) a2[n] = 0.f;
        mm_AB(ping, ufr, a2, w, lane);       // cur * u^2
        float d1 = m[2*i+1];
        float d0 = m[2*i] + (i == 0 ? -ls : 0.f);
        #pragma unroll
        for (int n = 0; n < 4; ++n)
            #pragma unroll
            for (int r = 0; r < 4; ++r) {
                float v = a2[n][r] + d1 * uD[n][r];
                if (n == w && lrow == 4*lq + r) v += d0;
                a2[n][r] = v;
            }
        if (i > 0) {
            store_sym(pong, a2, w, lane);
            __syncthreads();
            unsigned short* t = ping; ping = pong; pong = t;
        } else {
            #pragma unroll
            for (int n = 0; n < 4; ++n) accL[n] = a2[n];
        }
    }
}

// ---------------- K: partial sums ----------------
__global__ __launch_bounds__(256) void k_psum(const float* __restrict__ src,
                                              float* __restrict__ Pbuf) {
    int g = blockIdx.x, tid = threadIdx.x;
    float4 acc[4];
    #pragma unroll
    for (int e = 0; e < 4; ++e) acc[e] = make_float4(0.f, 0.f, 0.f, 0.f);
    for (int b = 0; b < MPB; ++b) {
        const float4* sb = (const float4*)(src + ((size_t)g*MPB + b)*4096);
        #pragma unroll
        for (int e = 0; e < 4; ++e) {
            float4 v = sb[e*256 + tid];
            acc[e].x += v.x; acc[e].y += v.y; acc[e].z += v.z; acc[e].w += v.w;
        }
    }
    #pragma unroll
    for (int e = 0; e < 4; ++e)
        *(float4*)(Pbuf + (size_t)g*4096 + (size_t)(e*256 + tid)*4) = acc[e];
}

// ---------------- K: hierarchical reduce (compile-time trip counts) --------
__global__ __launch_bounds__(256) void k_red1(const float* __restrict__ Pbuf,
                                              float* __restrict__ Pbuf2) {
    int b = blockIdx.x;
    int gb = b >> 4, cb = b & 15;
    int idx = cb*256 + threadIdx.x;
    float s = 0.f;
    #pragma unroll 8
    for (int g = 0; g < 64; ++g)
        s += Pbuf[(size_t)(gb*64 + g)*4096 + idx];
    Pbuf2[(size_t)gb*4096 + idx] = s;
}
__global__ __launch_bounds__(256) void k_red2(const float* __restrict__ Pbuf2,
                                              float* __restrict__ out4096,
                                              float inv) {
    int idx = blockIdx.x*256 + threadIdx.x;
    float s = 0.f;
    #pragma unroll
    for (int gb = 0; gb < 16; ++gb) s += Pbuf2[(size_t)gb*4096 + idx];
    out4096[idx] = s * inv;
}

// ---------------- fp32 helpers for prep kernels ----------------
__device__ __forceinline__ void mm_tile(const float* __restrict__ A,
                                        const float* __restrict__ B,
                                        float acc[16], int ti, int tj) {
    #pragma unroll
    for (int e = 0; e < 16; ++e) acc[e] = 0.f;
    const float* Ab = A + (4*ti)*PITCHF;
    const float* Bb = B + 4*tj;
    #pragma unroll 4
    for (int k0 = 0; k0 < 64; k0 += 4) {
        float4 a0 = *(const float4*)(Ab + 0*PITCHF + k0);
        float4 a1 = *(const float4*)(Ab + 1*PITCHF + k0);
        float4 a2 = *(const float4*)(Ab + 2*PITCHF + k0);
        float4 a3 = *(const float4*)(Ab + 3*PITCHF + k0);
        float4 b0 = *(const float4*)(Bb + (k0+0)*PITCHF);
        float4 b1 = *(const float4*)(Bb + (k0+1)*PITCHF);
        float4 b2 = *(const float4*)(Bb + (k0+2)*PITCHF);
        float4 b3 = *(const float4*)(Bb + (k0+3)*PITCHF);
#define MMROW(RO, AV) \
        acc[RO+0] += AV.x*b0.x + AV.y*b1.x + AV.z*b2.x + AV.w*b3.x; \
        acc[RO+1] += AV.x*b0.y + AV.y*b1.y + AV.z*b2.y + AV.w*b3.y; \
        acc[RO+2] += AV.x*b0.z + AV.y*b1.z + AV.z*b2.z + AV.w*b3.z; \
        acc[RO+3] += AV.x*b0.w + AV.y*b1.w + AV.z*b2.w + AV.w*b3.w;
        MMROW(0, a0) MMROW(4, a1) MMROW(8, a2) MMROW(12, a3)
#undef MMROW
    }
}
__device__ __forceinline__ void store_tile(float* __restrict__ D,
                                           const float acc[16], int ti, int tj) {
    #pragma unroll
    for (int r = 0; r < 4; ++r) {
        float4 v = make_float4(acc[r*4+0], acc[r*4+1], acc[r*4+2], acc[r*4+3]);
        *(float4*)(D + (4*ti+r)*PITCHF + 4*tj) = v;
    }
}
__device__ __forceinline__ float block_trace64(const float* __restrict__ W,
                                               float* red, int tid) {
    if (tid < 64) {
        float v = W[tid*PITCHF + tid];
        #pragma unroll
        for (int off = 32; off; off >>= 1) v += __shfl_xor(v, off);
        if (tid == 0) red[0] = v;
    }
    __syncthreads();
    float t = red[0];
    __syncthreads();
    return t;
}

// ---------------- K: S = M0^{1/2}, SI = M0^{-1/2} ----------------
__global__ __launch_bounds__(256) void k_prep1(const float* __restrict__ M0,
                                               float* __restrict__ S,
                                               float* __restrict__ SI) {
    __shared__ __align__(16) float WS[4*FMSZ];
    __shared__ float red[256];
    float* W0 = WS; float* W1 = WS + FMSZ; float* W2 = WS + 2*FMSZ; float* W3 = WS + 3*FMSZ;
    int tid = threadIdx.x;
    int ti = tid >> 4, tj = tid & 15;
    const float4* s4 = (const float4*)M0;
    #pragma unroll
    for (int e = 0; e < 4; ++e) {
        int idx = e*256 + tid;
        *(float4*)(W0 + (idx>>4)*PITCHF + (idx&15)*4) = s4[idx];
    }
    __syncthreads();
    float m = block_trace64(W0, red, tid) * (1.f/64.f);
    float im = 1.f/m;
    #pragma unroll
    for (int r = 0; r < 4; ++r) {
        float4 v = *(const float4*)(W0 + (4*ti+r)*PITCHF + 4*tj);
        v.x *= im; v.y *= im; v.z *= im; v.w *= im;
        if (ti == tj) ((float*)&v)[r] -= 1.f;
        *(float4*)(W0 + (4*ti+r)*PITCHF + 4*tj) = v;
    }
    __syncthreads();
    float acc[16];
    mm_tile(W0, W0, acc, ti, tj); store_tile(W1, acc, ti, tj); __syncthreads();
    mm_tile(W0, W1, acc, ti, tj); store_tile(W2, acc, ti, tj); __syncthreads();
    mm_tile(W1, W1, acc, ti, tj); store_tile(W3, acc, ti, tj); __syncthreads();
    float sm = sqrtf(m), rm = rsqrtf(m);
    #pragma unroll
    for (int r = 0; r < 4; ++r) {
        float4 e1 = *(const float4*)(W0 + (4*ti+r)*PITCHF + 4*tj);
        float4 e2 = *(const float4*)(W1 + (4*ti+r)*PITCHF + 4*tj);
        float4 e3 = *(const float4*)(W2 + (4*ti+r)*PITCHF + 4*tj);
        float4 e4 = *(const float4*)(W3 + (4*ti+r)*PITCHF + 4*tj);
        float4 sv, iv;
        #pragma unroll
        for (int c = 0; c < 4; ++c) {
            float E1 = ((float*)&e1)[c], E2 = ((float*)&e2)[c];
            float E3 = ((float*)&e3)[c], E4 = ((float*)&e4)[c];
            float d = (ti == tj && c == r) ? 1.f : 0.f;
            ((float*)&sv)[c] = sm*(d + 0.5f*E1 - 0.125f*E2 + 0.0625f*E3 - 0.0390625f*E4);
            ((float*)&iv)[c] = rm*(d - 0.5f*E1 + 0.375f*E2 - 0.3125f*E3 + 0.2734375f*E4);
        }
        *(float4*)(S  + (4*ti+r)*64 + 4*tj) = sv;
        *(float4*)(SI + (4*ti+r)*64 + 4*tj) = iv;
    }
}

// ---------------- K: expT, mean = S expT S, MI = mean^{-1/2} ----------------
__global__ __launch_bounds__(256) void k_prep2(const float* __restrict__ T,
                                               const float* __restrict__ S,
                                               float* __restrict__ MI) {
    __shared__ __align__(16) float WS[4*FMSZ];
    __shared__ float red[256];
    float* W0 = WS; float* W1 = WS + FMSZ; float* W2 = WS + 2*FMSZ; float* W3 = WS + 3*FMSZ;
    int tid = threadIdx.x;
    int ti = tid >> 4, tj = tid & 15;
    const float4* t4 = (const float4*)T;
    #pragma unroll
    for (int e = 0; e < 4; ++e) {
        int idx = e*256 + tid;
        *(float4*)(W0 + (idx>>4)*PITCHF + (idx&15)*4) = t4[idx];
    }
    __syncthreads();
    float g = block_trace64(W0, red, tid) * (1.f/64.f);
    if (ti == tj) {
        #pragma unroll
        for (int r = 0; r < 4; ++r) W0[(4*ti+r)*PITCHF + 4*tj + r] -= g;
    }
    __syncthreads();
    float acc[16];
    mm_tile(W0, W0, acc, ti, tj); store_tile(W1, acc, ti, tj); __syncthreads();
    mm_tile(W0, W1, acc, ti, tj); store_tile(W2, acc, ti, tj); __syncthreads();
    mm_tile(W1, W1, acc, ti, tj); store_tile(W3, acc, ti, tj); __syncthreads();
    float eg = expf(g);
    #pragma unroll
    for (int r = 0; r < 4; ++r) {
        float4 f1 = *(const float4*)(W0 + (4*ti+r)*PITCHF + 4*tj);
        float4 f2 = *(const float4*)(W1 + (4*ti+r)*PITCHF + 4*tj);
        float4 f3 = *(const float4*)(W2 + (4*ti+r)*PITCHF + 4*tj);
        float4 f4 = *(const float4*)(W3 + (4*ti+r)*PITCHF + 4*tj);
        float4 v;
        #pragma unroll
        for (int c = 0; c < 4; ++c) {
            float d = (ti == tj && c == r) ? 1.f : 0.f;
            ((float*)&v)[c] = eg*(d + ((float*)&f1)[c] + 0.5f*((float*)&f2)[c]
                                  + (1.f/6.f)*((float*)&f3)[c] + (1.f/24.f)*((float*)&f4)[c]);
        }
        *(float4*)(W1 + (4*ti+r)*PITCHF + 4*tj) = v;
    }
    __syncthreads();
    const float4* s4 = (const float4*)S;
    #pragma unroll
    for (int e = 0; e < 4; ++e) {
        int idx = e*256 + tid;
        *(float4*)(W2 + (idx>>4)*PITCHF + (idx&15)*4) = s4[idx];
    }
    __syncthreads();
    mm_tile(W2, W1, acc, ti, tj); store_tile(W3, acc, ti, tj); __syncthreads();
    mm_tile(W3, W2, acc, ti, tj); store_tile(W0, acc, ti, tj); __syncthreads();
    float m2 = block_trace64(W0, red, tid) * (1.f/64.f);
    float im2 = 1.f/m2;
    #pragma unroll
    for (int r = 0; r < 4; ++r) {
        float4 v = *(const float4*)(W0 + (4*ti+r)*PITCHF + 4*tj);
        v.x *= im2; v.y *= im2; v.z *= im2; v.w *= im2;
        if (ti == tj) ((float*)&v)[r] -= 1.f;
        *(float4*)(W0 + (4*ti+r)*PITCHF + 4*tj) = v;
    }
    __syncthreads();
    mm_tile(W0, W0, acc, ti, tj); store_tile(W1, acc, ti, tj); __syncthreads();
    mm_tile(W0, W1, acc, ti, tj); store_tile(W2, acc, ti, tj); __syncthreads();
    mm_tile(W1, W1, acc, ti, tj); store_tile(W3, acc, ti, tj); __syncthreads();
    float rm = rsqrtf(m2);
    #pragma unroll
    for (int r = 0; r < 4; ++r) {
        float4 g1 = *(const float4*)(W0 + (4*ti+r)*PITCHF + 4*tj);
        float4 g2 = *(const float4*)(W1 + (4*ti+r)*PITCHF + 4*tj);
        float4 g3 = *(const float4*)(W2 + (4*ti+r)*PITCHF + 4*tj);
        float4 g4 = *(const float4*)(W3 + (4*ti+r)*PITCHF + 4*tj);
        float4 v;
        #pragma unroll
        for (int c = 0; c < 4; ++c) {
            float d = (ti == tj && c == r) ? 1.f : 0.f;
            ((float*)&v)[c] = rm*(d - 0.5f*((float*)&g1)[c] + 0.375f*((float*)&g2)[c]
                                  - 0.3125f*((float*)&g3)[c] + 0.2734375f*((float*)&g4)[c]);
        }
        *(float4*)(MI + (4*ti+r)*64 + 4*tj) = v;
    }
}

// ---------------- K: phase C — accumulate sum_b log(SI x_b SI), deg-9 ------
__global__ __launch_bounds__(256, 4) void k_phaseC(const float* __restrict__ x,
        const float* __restrict__ SI, float* __restrict__ Pbuf,
        const Poly16 PL, float invh, float cdh) {
    __shared__ __align__(16) unsigned short W0[BMSZ], W2[BMSZ];
    __shared__ float red[4];
    const int tid = threadIdx.x, w = tid >> 6, lane = tid & 63;
    const int lrow = lane & 15, lq = lane >> 4;
    const float4* si4 = (const float4*)SI;
    #pragma unroll
    for (int e = 0; e < 4; ++e) {
        int idx = e*256 + tid;
        float4 sv = si4[idx];
        *(uint2*)(W0 + (idx>>4)*PITCHB + (idx&15)*4) = pack4(sv.x, sv.y, sv.z, sv.w);
    }
    __syncthreads();
    bf16x8 sifr[8];
    load_frags(W0, sifr, lane);
    f32x4 lacc[4];
    #pragma unroll
    for (int n = 0; n < 4; ++n) lacc[n] = 0.f;
    for (int mloc = 0; mloc < MPB; ++mloc) {
        size_t b = (size_t)blockIdx.x*MPB + mloc;
        __syncthreads();
        f32x4 accL[4];
        log_core<5>((const float4*)(x + b*4096), sifr, W0, W2, red,
                    PL.m, invh, cdh, accL, tid, w, lane);
        #pragma unroll
        for (int n = 0; n < 4; ++n) lacc[n] += accL[n];
    }
    float* pb = Pbuf + (size_t)blockIdx.x*4096;
    #pragma unroll
    for (int n = 0; n < 4; ++n)
        *(float4*)(pb + (16*n + lrow)*64 + 16*w + 4*lq) =
            make_float4(lacc[n][0], lacc[n][1], lacc[n][2], lacc[n][3]);
}

// ---------------- K: phase E1 — dist_b, L_b (deg-9) ------------------------
__global__ __launch_bounds__(256, 4) void k_phaseE1(const float* __restrict__ x,
        const float* __restrict__ MIm, float* __restrict__ Dist,
        unsigned short* Lbf, const Poly16 PL, float invh, float cdh) {
    __shared__ __align__(16) unsigned short W0[BMSZ], W2[BMSZ];
    __shared__ float red[4];
    const int tid = threadIdx.x, w = tid >> 6, lane = tid & 63;
    const int lrow = lane & 15, lq = lane >> 4;
    const float4* mi4 = (const float4*)MIm;
    #pragma unroll
    for (int e = 0; e < 4; ++e) {
        int idx = e*256 + tid;
        float4 sv = mi4[idx];
        *(uint2*)(W0 + (idx>>4)*PITCHB + (idx&15)*4) = pack4(sv.x, sv.y, sv.z, sv.w);
    }
    __syncthreads();
    bf16x8 sifr[8];
    load_frags(W0, sifr, lane);
    for (int mloc = 0; mloc < MPB; ++mloc) {
        size_t b = (size_t)blockIdx.x*MPB + mloc;
        __syncthreads();
        f32x4 accL[4];
        log_core<5>((const float4*)(x + b*4096), sifr, W0, W2, red,
                    PL.m, invh, cdh, accL, tid, w, lane);
        float sq = 0.f;
        #pragma unroll
        for (int n = 0; n < 4; ++n)
            #pragma unroll
            for (int r = 0; r < 4; ++r) sq += accL[n][r]*accL[n][r];
        #pragma unroll
        for (int off = 32; off; off >>= 1) sq += __shfl_xor(sq, off);
        if (lane == 0) red[w] = sq;
        __syncthreads();
        if (tid == 0) Dist[b] = red[0] + red[1] + red[2] + red[3];
        unsigned short* Lb = Lbf + (size_t)blockIdx.x*65536 + (size_t)mloc*4096;
        #pragma unroll
        for (int n = 0; n < 4; ++n)
            *(uint2*)(Lb + (16*n + lrow)*64 + 16*w + 4*lq) =
                pack4(accL[n][0], accL[n][1], accL[n][2], accL[n][3]);
    }
}

// ---------------- K: var/std/p ----------------
__global__ __launch_bounds__(256) void k_var(const float* __restrict__ Dist,
                                             const float* __restrict__ scale,
                                             float* __restrict__ PV) {
    __shared__ float red[256];
    int tid = threadIdx.x;
    float s = 0.f;
    for (int k = tid; k < NMAT; k += 256) s += Dist[k];
    red[tid] = s;
    __syncthreads();
    for (int off = 128; off > 0; off >>= 1) {
        if (tid < off) red[tid] += red[tid + off];
        __syncthreads();
    }
    if (tid == 0) {
        float var = red[0] / (float)NMAT;
        PV[0] = scale[0] / (sqrtf(var) + 1e-5f);
    }
}

// ---------------- K: phase E2 — out = exp(p L), deg-5, 2 LDS buffers -------
__global__ __launch_bounds__(256, 4) void k_phaseE2(const unsigned short* __restrict__ Lbf,
        const float* __restrict__ PV, float* __restrict__ out, const Poly16 PE) {
    __shared__ __align__(16) unsigned short W0[BMSZ], W1[BMSZ];
    const int tid = threadIdx.x, w = tid >> 6, lane = tid & 63;
    const int lrow = lane & 15, lq = lane >> 4;
    const float p = PV[0];
    for (int mloc = MPB-1; mloc >= 0; --mloc) {
        size_t b = (size_t)blockIdx.x*MPB + mloc;
        __syncthreads();
        const uint2* Lp = (const uint2*)(Lbf + (size_t)blockIdx.x*65536 + (size_t)mloc*4096);
        #pragma unroll
        for (int e = 0; e < 4; ++e) {
            int idx = e*256 + tid;
            uint2 q = Lp[idx];
            float v0 = p * bfu(q.x & 0xffffu);
            float v1 = p * bfu(q.x >> 16);
            float v2 = p * bfu(q.y & 0xffffu);
            float v3 = p * bfu(q.y >> 16);
            *(uint2*)(W0 + (idx>>4)*PITCHB + (idx&15)*4) = pack4(v0, v1, v2, v3);
        }
        __syncthreads();
        f32x4 MD[4];
        #pragma unroll
        for (int n = 0; n < 4; ++n) {
            uint2 q = *(const uint2*)(W0 + (16*n + lrow)*PITCHB + 16*w + 4*lq);
            MD[n][0] = bfu(q.x & 0xffffu);
            MD[n][1] = bfu(q.x >> 16);
            MD[n][2] = bfu(q.y & 0xffffu);
            MD[n][3] = bfu(q.y >> 16);
        }
        f32x4 acc[4];
        #pragma unroll
        for (int n = 0; n < 4; ++n) acc[n] = 0.f;
        mm_LL(W0, W0, acc, w, lane);               // M^2
        store_sym(W1, acc, w, lane);
        __syncthreads();
        bf16x8 mfr[8];
        load_frags(W1, mfr, lane);                 // M^2 -> regs; W1 free
        f32x4 cur[4];
        {
            // deg-5: chunks C2..C0, C2 = m[4] I + m[5] M
            float c1 = PE.m[5], c0 = PE.m[4];
            #pragma unroll
            for (int n = 0; n < 4; ++n)
                #pragma unroll
                for (int r = 0; r < 4; ++r) {
                    float v = c1 * MD[n][r];
                    if (n == w && lrow == 4*lq + r) v += c0;
                    cur[n][r] = v;
                }
        }
        store_sym(W0, cur, w, lane);               // M reads done pre-barrier
        __syncthreads();
        unsigned short* ping = W0;
        unsigned short* pong = W1;
        f32x4 accO[4];
        #pragma unroll
        for (int i = 1; i >= 0; --i) {
            f32x4 a2[4];
            #pragma unroll
            for (int n = 0; n < 4; ++n) a2[n] = 0.f;
            mm_AB(ping, mfr, a2, w, lane);
            float d1 = PE.m[2*i+1], d0 = PE.m[2*i];
            #pragma unroll
            for (int n = 0; n < 4; ++n)
                #pragma unroll
                for (int r = 0; r < 4; ++r) {
                    float v = a2[n][r] + d1 * MD[n][r];
                    if (n == w && lrow == 4*lq + r) v += d0;
                    a2[n][r] = v;
                }
            if (i > 0) {
                store_sym(pong, a2, w, lane);
                __syncthreads();
                unsigned short* t = ping; ping = pong; pong = t;
            } else {
                #pragma unroll
                for (int n = 0; n < 4; ++n) accO[n] = a2[n];
            }
        }
        float* ob = out + b*4096;
        #pragma unroll
        for (int n = 0; n < 4; ++n)
            *(float4*)(ob + (16*n + lrow)*64 + 16*w + 4*lq) =
                make_float4(accO[n][0], accO[n][1], accO[n][2], accO[n][3]);
    }
}

// ---------------- host launch ----------------
extern "C" void kernel_launch(void* const* d_in, const int* in_sizes, int n_in,
                              void* d_out, int out_size, void* d_ws, size_t ws_size,
                              hipStream_t stream) {
    const float* x = (const float*)d_in[0];
    const float* scale = (const float*)d_in[1];
    float* out = (float*)d_out;
    float* ws = (float*)d_ws;

    float* M0  = ws;            // 4096
    float* S   = M0 + 4096;     // 4096
    float* SI  = S + 4096;      // 4096
    float* T   = SI + 4096;     // 4096
    float* MIm = T + 4096;      // 4096
    float* DIST = MIm + 4096;   // 8192
    float* PV  = DIST + NMAT;   // 1
    float* Pbuf  = out;                            // 1024 partials
    float* Pbuf2 = out + (size_t)1024*4096;        // 16 stage-1 partials
    unsigned short* Lbf = (unsigned short*)d_out;  // region-interleaved L

    // exact Chebyshev-of-log on [0.25, 3.8] -> monomial coeffs (host, double)
    const double A = 0.25, B = 3.8;
    const double ccd = 0.5*(A+B), hhd = 0.5*(B-A);
    const double Md = ccd/hhd;
    const double tau = Md - sqrt(Md*Md - 1.0);
    double ac[16];
    ac[0] = log(hhd/(2.0*tau));
    {
        double tp = 1.0;
        for (int n = 1; n < 16; ++n) { tp *= -tau; ac[n] = -2.0*tp/(double)n; }
    }
    double Tm[16][16];
    for (int i = 0; i < 16; ++i) for (int k = 0; k < 16; ++k) Tm[i][k] = 0.0;
    Tm[0][0] = 1.0; Tm[1][1] = 1.0;
    for (int n = 2; n < 16; ++n)
        for (int k = 0; k <= n; ++k)
            Tm[n][k] = 2.0*(k > 0 ? Tm[n-1][k-1] : 0.0) - Tm[n-2][k];
    double m9[16];
    for (int k = 0; k < 16; ++k) m9[k] = 0.0;
    for (int n = 0; n < 10; ++n)
        for (int k = 0; k <= n; ++k) m9[k] += ac[n]*Tm[n][k];
    Poly16 PL9, PEXP;
    for (int k = 0; k < 16; ++k) { PL9.m[k] = (float)m9[k]; PEXP.m[k] = 0.f; }
    double fact = 1.0;
    for (int k = 0; k < 6; ++k) {            // deg-5 Taylor
        if (k > 0) fact *= (double)k;
        PEXP.m[k] = (float)(1.0/fact);
    }
    const float invh = (float)(1.0/hhd);
    const float cdh  = (float)(ccd/hhd);

    k_psum<<<NBLK, 256, 0, stream>>>(x, Pbuf);
    k_red1<<<256, 256, 0, stream>>>(Pbuf, Pbuf2);
    k_red2<<<16, 256, 0, stream>>>(Pbuf2, M0, 1.f/(float)NMAT);
    k_prep1<<<1, 256, 0, stream>>>(M0, S, SI);
    k_phaseC<<<NBLK, 256, 0, stream>>>(x, SI, Pbuf, PL9, invh, cdh);
    k_red1<<<256, 256, 0, stream>>>(Pbuf, Pbuf2);
    k_red2<<<16, 256, 0, stream>>>(Pbuf2, T, 1.f/(float)NMAT);
    k_prep2<<<1, 256, 0, stream>>>(T, S, MIm);
    k_phaseE1<<<NBLK, 256, 0, stream>>>(x, MIm, DIST, Lbf, PL9, invh, cdh);
    k_var<<<1, 256, 0, stream>>>(DIST, scale, PV);
    k_phaseE2<<<NBLK, 256, 0, stream>>>(Lbf, PV, out, PEXP);
}